// Round 3
// baseline (392.207 us; speedup 1.0000x reference)
//
#include <hip/hip_runtime.h>
#include <hip/hip_bf16.h>
#include <math.h>

typedef __bf16 bf16;
typedef __bf16 bf16x8 __attribute__((ext_vector_type(8)));
typedef float f32x4 __attribute__((ext_vector_type(4)));

#define MFMA(a,b,c) __builtin_amdgcn_mfma_f32_16x16x32_bf16(a,b,c,0,0,0)

static __device__ __forceinline__ int swz256(int row, int kb){ return row*256 + (kb ^ ((row&7)<<4)); }
static __device__ __forceinline__ int swz128(int row, int kb){ return row*128 + (kb ^ ((row&7)<<4)); }
static __device__ __forceinline__ int swz64 (int row, int kb){ return row*64  + (kb ^ ((row&3)<<4)); }

// ---------------- weight pack: W (KxN row-major f32) -> fragment-ordered bf16 ----------------
__global__ void k_pack(const float* __restrict__ W, bf16* __restrict__ outp, int K, int N) {
    int idx = blockIdx.x*256 + threadIdx.x;
    int total = (N >> 4) * (K >> 5) * 64;
    if (idx >= total) return;
    int l = idx & 63, f = idx >> 6;
    int KF = K >> 5;
    int kf = f % KF, nf = f / KF;
    int n = nf*16 + (l & 15), k0 = kf*32 + (l >> 4)*8;
    bf16x8 v;
    for (int j = 0; j < 8; ++j) v[j] = (bf16)W[(size_t)(k0+j)*N + n];
    *(bf16x8*)(outp + (size_t)idx*8) = v;
}

// ---------------- bias gather ----------------
__global__ void k_bias(const float* __restrict__ table, const int* __restrict__ ridx,
                       float* __restrict__ bias49) {
    int idx = blockIdx.x*256 + threadIdx.x;
    if (idx >= 2401) return;
    int ri = ridx[idx];
    for (int h = 0; h < 4; ++h) bias49[h*2401 + idx] = table[ri*4 + h];
}

// ---------------- zero pad rows 49..63 of each window in xw ----------------
__global__ void k_zero(uint4* __restrict__ xw4) {
    int idx = blockIdx.x*256 + threadIdx.x;
    if (idx >= 2048*240) return;
    int win = idx / 240, rem = idx - win*240;
    xw4[(size_t)win*1024 + 784 + rem] = make_uint4(0,0,0,0);
}

// ---------------- LN1 + shift + window partition ----------------
__global__ void __launch_bounds__(256) k_ln1(const float* __restrict__ x,
                                             const float* __restrict__ g1,
                                             const float* __restrict__ b1,
                                             bf16* __restrict__ xw) {
    __shared__ float T[128*113];
    __shared__ float meanL[112], rstdL[112];
    __shared__ float gL[128], bL[128];
    int tid = threadIdx.x;
    int b = blockIdx.x / 112, h = blockIdx.x - (blockIdx.x/112)*112;
    if (tid < 128) { gL[tid] = g1[tid]; bL[tid] = b1[tid]; }
    const float* xp = x + (size_t)b*128*12544 + h*112;
    for (int e = tid; e < 14336; e += 256) {
        int c = e / 112, w = e - c*112;
        T[c*113 + w] = xp[(size_t)c*12544 + w];
    }
    __syncthreads();
    if (tid < 224) {
        int w = tid >> 1, q = tid & 1;
        float s = 0.f, s2 = 0.f;
        for (int i = 0; i < 64; ++i) { float v = T[(q*64 + i)*113 + w]; s += v; s2 += v*v; }
        s  += __shfl_xor(s, 1, 64);
        s2 += __shfl_xor(s2, 1, 64);
        if (q == 0) {
            float m = s * 0.0078125f;
            float var = s2 * 0.0078125f - m*m;
            meanL[w] = m; rstdL[w] = rsqrtf(var + 1e-5f);
        }
    }
    __syncthreads();
    int hr = h + 109; if (hr >= 112) hr -= 112;
    int wh = hr / 7, nr = hr - wh*7;
    for (int e = tid; e < 14336; e += 256) {
        int w = e >> 7, c = e & 127;
        int wr = w + 109; if (wr >= 112) wr -= 112;
        int wwi = wr / 7, nc = wr - wwi*7;
        int win = b*256 + wh*16 + wwi;
        int n = nr*7 + nc;
        float v = (T[c*113 + w] - meanL[w]) * rstdL[w] * gL[c] + bL[c];
        xw[((size_t)win*64 + n)*128 + c] = (bf16)v;
    }
}

// ---------------- fused window attention v2: 48KB LDS, <=128 VGPR ----------------
// one block per window (2048), 4 waves, wave = head
__global__ void __launch_bounds__(256, 4) k_attn(const bf16* __restrict__ xw,
                                              const bf16x8* __restrict__ wqkv,
                                              const float* __restrict__ qkv_b,
                                              const bf16x8* __restrict__ wproj,
                                              const float* __restrict__ proj_b,
                                              const float* __restrict__ bias49,
                                              bf16* __restrict__ x1p) {
    __shared__ char lds[49152];
    const int tid = threadIdx.x;
    const int l = tid & 63, wv = tid >> 6;
    const int win = blockIdx.x;
    const int lrow = l & 15, lk = l >> 4;
    char* X  = lds;                          // [64][128] bf16 swz256 (stage 0-1)
    char* VT = lds + wv*4096;                // [32][64] bf16 swz128, overlays X after barrier
    char* Q  = lds + 16384 + wv*8192;        // [64][32] bf16 swz64
    char* Kt = Q + 4096;                     // [64][32] bf16 swz64
    char* P  = Q;                            // [64][64] bf16 swz128 (overlays own Q/Kt)
    char* O  = lds + 16384;                  // [64][128] bf16 swz256 (overlays waves 0-1 P)

    // stage 0: load window tile (zero-padded rows 49..63)
    {
        const uint4* src = (const uint4*)(xw + (size_t)win*8192);
        for (int it = 0; it < 4; ++it) {
            int unit = it*256 + tid;
            int row = unit >> 4, s = unit & 15;
            *(uint4*)(X + swz256(row, s*16)) = src[unit];
        }
    }
    __syncthreads();

    // stage 1a: q,k GEMM -> write Q,Kt (own-wave region, no barrier needed)
    {
        f32x4 qa[4][2], ka[4][2];
        float qb0 = qkv_b[      wv*32 + lrow], qb1 = qkv_b[      wv*32 + 16 + lrow];
        float kb0 = qkv_b[128 + wv*32 + lrow], kb1 = qkv_b[128 + wv*32 + 16 + lrow];
        for (int mf = 0; mf < 4; ++mf) for (int r = 0; r < 4; ++r) {
            qa[mf][0][r] = qb0; qa[mf][1][r] = qb1;
            ka[mf][0][r] = kb0; ka[mf][1][r] = kb1;
        }
        for (int kk = 0; kk < 4; ++kk) {
            bf16x8 a[4];
            for (int mf = 0; mf < 4; ++mf)
                a[mf] = *(const bf16x8*)(X + swz256(mf*16 + lrow, kk*64 + lk*16));
            for (int nf2 = 0; nf2 < 2; ++nf2) {
                bf16x8 bq = wqkv[(( (    wv*2 + nf2)*4 + kk)*64) + l];
                bf16x8 bk = wqkv[(( (8 + wv*2 + nf2)*4 + kk)*64) + l];
                for (int mf = 0; mf < 4; ++mf) {
                    qa[mf][nf2] = MFMA(a[mf], bq, qa[mf][nf2]);
                    ka[mf][nf2] = MFMA(a[mf], bk, ka[mf][nf2]);
                }
            }
        }
        const float scale = 0.17677669529663687f;
        for (int mf = 0; mf < 4; ++mf) for (int nf2 = 0; nf2 < 2; ++nf2)
            for (int r = 0; r < 4; ++r) {
                int row = mf*16 + lk*4 + r;
                int col = nf2*16 + lrow;
                *(bf16*)(Q  + swz64(row, col*2)) = (bf16)(qa[mf][nf2][r] * scale);
                *(bf16*)(Kt + swz64(row, col*2)) = (bf16)(ka[mf][nf2][r]);
            }
    }
    // stage 1b: v GEMM
    f32x4 va[4][2];
    {
        float vb0 = qkv_b[256 + wv*32 + lrow], vb1 = qkv_b[256 + wv*32 + 16 + lrow];
        for (int mf = 0; mf < 4; ++mf) for (int r = 0; r < 4; ++r) {
            va[mf][0][r] = vb0; va[mf][1][r] = vb1;
        }
        for (int kk = 0; kk < 4; ++kk) {
            bf16x8 a[4];
            for (int mf = 0; mf < 4; ++mf)
                a[mf] = *(const bf16x8*)(X + swz256(mf*16 + lrow, kk*64 + lk*16));
            for (int nf2 = 0; nf2 < 2; ++nf2) {
                bf16x8 bv = wqkv[(((16 + wv*2 + nf2)*4 + kk)*64) + l];
                for (int mf = 0; mf < 4; ++mf)
                    va[mf][nf2] = MFMA(a[mf], bv, va[mf][nf2]);
            }
        }
    }
    __syncthreads();   // all X reads done across waves -> VT may overwrite X
    for (int mf = 0; mf < 4; ++mf) for (int nf2 = 0; nf2 < 2; ++nf2)
        for (int r = 0; r < 4; ++r) {
            int row = mf*16 + lk*4 + r;
            int col = nf2*16 + lrow;
            *(bf16*)(VT + swz128(col, row*2)) = (bf16)(va[mf][nf2][r]);
        }

    // stage 2: S = q k^T + bias ; softmax (own-wave Q/Kt; in-order ds ops make P overlay safe)
    f32x4 s[4][4];
    {
        const float* bh = bias49 + wv*2401;
        for (int mf = 0; mf < 4; ++mf) for (int nf = 0; nf < 4; ++nf)
            for (int r = 0; r < 4; ++r) {
                int row = mf*16 + lk*4 + r, col = nf*16 + lrow;
                float bv;
                if (col >= 49) bv = -1e30f;
                else if (row < 49) bv = bh[row*49 + col];
                else bv = 0.f;
                s[mf][nf][r] = bv;
            }
        bf16x8 aq[4], bk4[4];
        for (int mf = 0; mf < 4; ++mf) aq[mf]  = *(const bf16x8*)(Q  + swz64(mf*16 + lrow, lk*16));
        for (int nf = 0; nf < 4; ++nf) bk4[nf] = *(const bf16x8*)(Kt + swz64(nf*16 + lrow, lk*16));
        for (int mf = 0; mf < 4; ++mf) for (int nf = 0; nf < 4; ++nf)
            s[mf][nf] = MFMA(aq[mf], bk4[nf], s[mf][nf]);
    }
    for (int mf = 0; mf < 4; ++mf) for (int r = 0; r < 4; ++r) {
        float mx = -3e38f;
        for (int nf = 0; nf < 4; ++nf) mx = fmaxf(mx, s[mf][nf][r]);
        for (int d = 1; d < 16; d <<= 1) mx = fmaxf(mx, __shfl_xor(mx, d, 64));
        float sum = 0.f;
        for (int nf = 0; nf < 4; ++nf) { float p = __expf(s[mf][nf][r] - mx); s[mf][nf][r] = p; sum += p; }
        for (int d = 1; d < 16; d <<= 1) sum += __shfl_xor(sum, d, 64);
        float inv = 1.0f / sum;
        for (int nf = 0; nf < 4; ++nf) s[mf][nf][r] *= inv;
    }
    for (int mf = 0; mf < 4; ++mf) for (int nf = 0; nf < 4; ++nf)
        for (int r = 0; r < 4; ++r) {
            int row = mf*16 + lk*4 + r, col = nf*16 + lrow;
            *(bf16*)(P + swz128(row, col*2)) = (bf16)(s[mf][nf][r]);
        }

    // stage 3: PV (reads own-wave P and VT)
    f32x4 o[4][2];
    for (int mf = 0; mf < 4; ++mf) for (int nf = 0; nf < 2; ++nf)
        for (int r = 0; r < 4; ++r) o[mf][nf][r] = 0.f;
    for (int kf = 0; kf < 2; ++kf) {
        bf16x8 ap[4], bv2[2];
        for (int mf = 0; mf < 4; ++mf)
            ap[mf] = *(const bf16x8*)(P + swz128(mf*16 + lrow, kf*64 + lk*16));
        for (int nf = 0; nf < 2; ++nf)
            bv2[nf] = *(const bf16x8*)(VT + swz128(nf*16 + lrow, kf*64 + lk*16));
        for (int mf = 0; mf < 4; ++mf) for (int nf = 0; nf < 2; ++nf)
            o[mf][nf] = MFMA(ap[mf], bv2[nf], o[mf][nf]);
    }
    __syncthreads();   // all P/VT reads done -> O may overwrite waves 0-1 P region
    for (int mf = 0; mf < 4; ++mf) for (int nf = 0; nf < 2; ++nf)
        for (int r = 0; r < 4; ++r) {
            int row = mf*16 + lk*4 + r, col = wv*32 + nf*16 + lrow;
            *(bf16*)(O + swz256(row, col*2)) = (bf16)(o[mf][nf][r]);
        }
    __syncthreads();   // full O in place

    // stage 4: proj + scatter
    f32x4 pr[4][2];
    {
        float pb0 = proj_b[wv*32 + lrow], pb1 = proj_b[wv*32 + 16 + lrow];
        for (int mf = 0; mf < 4; ++mf) for (int r = 0; r < 4; ++r) { pr[mf][0][r] = pb0; pr[mf][1][r] = pb1; }
    }
    for (int kk = 0; kk < 4; ++kk) {
        bf16x8 a[4];
        for (int mf = 0; mf < 4; ++mf)
            a[mf] = *(const bf16x8*)(O + swz256(mf*16 + lrow, kk*64 + lk*16));
        for (int nf = 0; nf < 2; ++nf) {
            bf16x8 bfr = wproj[(((wv*2 + nf)*4 + kk)*64) + l];
            for (int mf = 0; mf < 4; ++mf) pr[mf][nf] = MFMA(a[mf], bfr, pr[mf][nf]);
        }
    }
    {
        int b_ = win >> 8, wh = (win >> 4) & 15, ww = win & 15;
        for (int mf = 0; mf < 4; ++mf) for (int r = 0; r < 4; ++r) {
            int row = mf*16 + lk*4 + r;
            if (row < 49) {
                int nr = row / 7, nc = row - nr*7;
                int h = wh*7 + nr + 3; if (h >= 112) h -= 112;
                int w = ww*7 + nc + 3; if (w >= 112) w -= 112;
                size_t t = (size_t)b_*12544 + h*112 + w;
                for (int nf = 0; nf < 2; ++nf) {
                    int col = wv*32 + nf*16 + lrow;
                    x1p[t*128 + col] = (bf16)pr[mf][nf][r];
                }
            }
        }
    }
}

// ---------------- MLP v3: LDS-resident XN, 32KB LDS, <=128 VGPR ----------------
// one block per 64 tokens (1568 blocks), 4 waves
__global__ void __launch_bounds__(256, 4) k_mlp(const float* __restrict__ x,
                                             const bf16* __restrict__ x1p,
                                             const float* __restrict__ g2,
                                             const float* __restrict__ b2,
                                             const float* __restrict__ fc1_b,
                                             const float* __restrict__ fc2_b,
                                             const bf16x8* __restrict__ wfc1,
                                             const bf16x8* __restrict__ wfc2,
                                             float* __restrict__ out) {
    __shared__ char lds[32768];
    char* XN = lds;                      // [64][128] bf16 swz256 (LN2 output)
    char* Hq = lds + 16384;              // [64][128] bf16 swz256 (hidden quarter)
    char* OT = lds;                      // epilogue overlay: [128][64] f32, swizzled

    int tid = threadIdx.x;
    int l = tid & 63, wv = tid >> 6;
    int lrow = l & 15, lk = l >> 4;
    int blk = blockIdx.x;
    int b = blk / 196;
    int l0 = (blk - b*196) * 64;
    const float* xb = x + (size_t)b*128*12544 + l0;
    const bf16* xpb = x1p + ((size_t)b*12544 + l0)*128;

    // phase 1: x1 = x + x1p at A-frag positions; LN2 stats; normalize -> XN (LDS)
    for (int mf = 0; mf < 4; ++mf) {
        int t = mf*16 + lrow;
        float xv[4][8];
        float s = 0.f, s2 = 0.f;
        #pragma unroll
        for (int kk = 0; kk < 4; ++kk) {
            int c0 = kk*32 + lk*8;
            bf16x8 xpv = *(const bf16x8*)(xpb + t*128 + c0);
            #pragma unroll
            for (int j = 0; j < 8; ++j) {
                float v = xb[(size_t)(c0+j)*12544 + t] + (float)xpv[j];
                xv[kk][j] = v;
                s += v; s2 += v*v;
            }
        }
        s  += __shfl_xor(s, 16, 64);  s  += __shfl_xor(s, 32, 64);
        s2 += __shfl_xor(s2, 16, 64); s2 += __shfl_xor(s2, 32, 64);
        float m = s * 0.0078125f;
        float var = s2 * 0.0078125f - m*m;
        float rs = rsqrtf(var + 1e-5f);
        #pragma unroll
        for (int kk = 0; kk < 4; ++kk) {
            int c0 = kk*32 + lk*8;
            float4 gv0 = *(const float4*)(g2 + c0), gv1 = *(const float4*)(g2 + c0 + 4);
            float4 bv0 = *(const float4*)(b2 + c0), bv1 = *(const float4*)(b2 + c0 + 4);
            float gg[8] = {gv0.x,gv0.y,gv0.z,gv0.w,gv1.x,gv1.y,gv1.z,gv1.w};
            float bb[8] = {bv0.x,bv0.y,bv0.z,bv0.w,bv1.x,bv1.y,bv1.z,bv1.w};
            bf16x8 v8;
            #pragma unroll
            for (int j = 0; j < 8; ++j)
                v8[j] = (bf16)((xv[kk][j] - m) * rs * gg[j] + bb[j]);
            *(bf16x8*)(XN + swz256(t, kk*64 + lk*16)) = v8;
        }
    }
    __syncthreads();

    // FC1 -> GELU -> FC2 over 4 hidden quarters of 128
    f32x4 acc2[4][2];
    for (int mf = 0; mf < 4; ++mf) for (int nf = 0; nf < 2; ++nf) {
        float bv = fc2_b[wv*32 + nf*16 + lrow];
        for (int r = 0; r < 4; ++r) acc2[mf][nf][r] = bv;
    }
    for (int q = 0; q < 4; ++q) {
        f32x4 acc1[4][2];
        for (int mf = 0; mf < 4; ++mf) for (int nf = 0; nf < 2; ++nf) {
            float bv = fc1_b[q*128 + wv*32 + nf*16 + lrow];
            for (int r = 0; r < 4; ++r) acc1[mf][nf][r] = bv;
        }
        for (int kk = 0; kk < 4; ++kk) {
            bf16x8 a[4];
            for (int mf = 0; mf < 4; ++mf)
                a[mf] = *(const bf16x8*)(XN + swz256(mf*16 + lrow, kk*64 + lk*16));
            for (int nf = 0; nf < 2; ++nf) {
                int nfg = q*8 + wv*2 + nf;
                bf16x8 bw = wfc1[(nfg*4 + kk)*64 + l];
                for (int mf = 0; mf < 4; ++mf)
                    acc1[mf][nf] = MFMA(a[mf], bw, acc1[mf][nf]);
            }
        }
        if (q) __syncthreads();          // prior FC2 reads of Hq done
        for (int mf = 0; mf < 4; ++mf) for (int nf = 0; nf < 2; ++nf)
            for (int r = 0; r < 4; ++r) {
                int row = mf*16 + lk*4 + r, col = wv*32 + nf*16 + lrow;
                float v = acc1[mf][nf][r];
                float u = 0.7978845608f * (v + 0.044715f * v*v*v);
                float e2 = __expf(2.f * u);
                float th = 1.f - 2.f / (e2 + 1.f);
                v = 0.5f * v * (1.f + th);
                *(bf16*)(Hq + swz256(row, col*2)) = (bf16)v;
            }
        __syncthreads();
        for (int kk = 0; kk < 4; ++kk) {
            bf16x8 a[4];
            for (int mf = 0; mf < 4; ++mf)
                a[mf] = *(const bf16x8*)(Hq + swz256(mf*16 + lrow, kk*64 + lk*16));
            for (int nf = 0; nf < 2; ++nf) {
                bf16x8 bw = wfc2[(((wv*2 + nf)*16 + q*4 + kk)*64) + l];
                for (int mf = 0; mf < 4; ++mf)
                    acc2[mf][nf] = MFMA(a[mf], bw, acc2[mf][nf]);
            }
        }
    }
    __syncthreads();     // XN/Hq dead; OT overlays both

    // epilogue: out = acc2 + x + x1p; transpose via swizzled OT; coalesced NCHW store
    for (int mf = 0; mf < 4; ++mf) for (int nf = 0; nf < 2; ++nf) {
        int t0 = mf*16 + lk*4, c = wv*32 + nf*16 + lrow;
        float4 xo = *(const float4*)(xb + (size_t)c*12544 + t0);
        float xr[4] = {xo.x, xo.y, xo.z, xo.w};
        f32x4 v4;
        #pragma unroll
        for (int r = 0; r < 4; ++r)
            v4[r] = acc2[mf][nf][r] + xr[r] + (float)xpb[(t0+r)*128 + c];
        *(f32x4*)(OT + c*256 + ((t0*4) ^ ((c&15)<<4))) = v4;
    }
    __syncthreads();
    for (int it = 0; it < 32; ++it) {
        int e = it*256 + tid;
        int c = e >> 6, t = e & 63;
        float v = *(const float*)(OT + c*256 + ((t*4) ^ ((c&15)<<4)));
        out[(size_t)(b*128 + c)*12544 + l0 + t] = v;
    }
}

// ---------------- launch ----------------
extern "C" void kernel_launch(void* const* d_in, const int* in_sizes, int n_in,
                              void* d_out, int out_size, void* d_ws, size_t ws_size,
                              hipStream_t stream) {
    const float* x      = (const float*)d_in[0];
    const float* n1g    = (const float*)d_in[1];
    const float* n1b    = (const float*)d_in[2];
    const float* qkv_w  = (const float*)d_in[3];
    const float* qkv_b  = (const float*)d_in[4];
    const float* rtab   = (const float*)d_in[5];
    const int*   ridx   = (const int*)  d_in[6];
    const float* proj_w = (const float*)d_in[7];
    const float* proj_b = (const float*)d_in[8];
    const float* n2g    = (const float*)d_in[9];
    const float* n2b    = (const float*)d_in[10];
    const float* fc1_w  = (const float*)d_in[11];
    const float* fc1_b  = (const float*)d_in[12];
    const float* fc2_w  = (const float*)d_in[13];
    const float* fc2_b  = (const float*)d_in[14];
    float* out = (float*)d_out;
    char* ws = (char*)d_ws;

    bf16*  xw     = (bf16*)(ws);
    bf16*  x1p    = (bf16*)(ws + 33554432);
    bf16*  wqkv   = (bf16*)(ws + 59244544);
    bf16*  wproj  = (bf16*)(ws + 59342848);
    bf16*  wfc1   = (bf16*)(ws + 59375616);
    bf16*  wfc2   = (bf16*)(ws + 59506688);
    float* bias49 = (float*)(ws + 59637760);

    hipLaunchKernelGGL(k_pack, dim3(24), dim3(256), 0, stream, qkv_w,  wqkv,  128, 384);
    hipLaunchKernelGGL(k_pack, dim3(8),  dim3(256), 0, stream, proj_w, wproj, 128, 128);
    hipLaunchKernelGGL(k_pack, dim3(32), dim3(256), 0, stream, fc1_w,  wfc1,  128, 512);
    hipLaunchKernelGGL(k_pack, dim3(32), dim3(256), 0, stream, fc2_w,  wfc2,  512, 128);
    hipLaunchKernelGGL(k_bias, dim3(10), dim3(256), 0, stream, rtab, ridx, bias49);
    hipLaunchKernelGGL(k_zero, dim3(1920), dim3(256), 0, stream, (uint4*)xw);
    hipLaunchKernelGGL(k_ln1,  dim3(896),  dim3(256), 0, stream, x, n1g, n1b, xw);
    hipLaunchKernelGGL(k_attn, dim3(2048), dim3(256), 0, stream, xw, (const bf16x8*)wqkv,
                       qkv_b, (const bf16x8*)wproj, proj_b, bias49, x1p);
    hipLaunchKernelGGL(k_mlp,  dim3(1568), dim3(256), 0, stream, x, x1p, n2g, n2b,
                       fc1_b, fc2_b, (const bf16x8*)wfc1, (const bf16x8*)wfc2, out);
}

// Round 5
// 293.537 us; speedup vs baseline: 1.3361x; 1.3361x over previous
//
#include <hip/hip_runtime.h>
#include <hip/hip_bf16.h>
#include <math.h>

typedef __bf16 bf16;
typedef __bf16 bf16x8 __attribute__((ext_vector_type(8)));
typedef float f32x4 __attribute__((ext_vector_type(4)));

#define MFMA(a,b,c) __builtin_amdgcn_mfma_f32_16x16x32_bf16(a,b,c,0,0,0)

static __device__ __forceinline__ int swz256(int row, int kb){ return row*256 + (kb ^ ((row&7)<<4)); }
static __device__ __forceinline__ int swz128(int row, int kb){ return row*128 + (kb ^ ((row&7)<<4)); }
static __device__ __forceinline__ int swz64 (int row, int kb){ return row*64  + (kb ^ ((row&3)<<4)); }

// ---------------- weight pack: W (KxN row-major f32) -> fragment-ordered bf16 ----------------
__global__ void k_pack(const float* __restrict__ W, bf16* __restrict__ outp, int K, int N) {
    int idx = blockIdx.x*256 + threadIdx.x;
    int total = (N >> 4) * (K >> 5) * 64;
    if (idx >= total) return;
    int l = idx & 63, f = idx >> 6;
    int KF = K >> 5;
    int kf = f % KF, nf = f / KF;
    int n = nf*16 + (l & 15), k0 = kf*32 + (l >> 4)*8;
    bf16x8 v;
    for (int j = 0; j < 8; ++j) v[j] = (bf16)W[(size_t)(k0+j)*N + n];
    *(bf16x8*)(outp + (size_t)idx*8) = v;
}

// ---------------- bias gather ----------------
__global__ void k_bias(const float* __restrict__ table, const int* __restrict__ ridx,
                       float* __restrict__ bias49) {
    int idx = blockIdx.x*256 + threadIdx.x;
    if (idx >= 2401) return;
    int ri = ridx[idx];
    for (int h = 0; h < 4; ++h) bias49[h*2401 + idx] = table[ri*4 + h];
}

// ---------------- zero pad rows 49..63 of each window in xw ----------------
__global__ void k_zero(uint4* __restrict__ xw4) {
    int idx = blockIdx.x*256 + threadIdx.x;
    if (idx >= 2048*240) return;
    int win = idx / 240, rem = idx - win*240;
    xw4[(size_t)win*1024 + 784 + rem] = make_uint4(0,0,0,0);
}

// ---------------- LN1 + shift + window partition ----------------
__global__ void __launch_bounds__(256) k_ln1(const float* __restrict__ x,
                                             const float* __restrict__ g1,
                                             const float* __restrict__ b1,
                                             bf16* __restrict__ xw) {
    __shared__ float T[128*113];
    __shared__ float meanL[112], rstdL[112];
    __shared__ float gL[128], bL[128];
    int tid = threadIdx.x;
    int b = blockIdx.x / 112, h = blockIdx.x - (blockIdx.x/112)*112;
    if (tid < 128) { gL[tid] = g1[tid]; bL[tid] = b1[tid]; }
    const float* xp = x + (size_t)b*128*12544 + h*112;
    for (int e = tid; e < 14336; e += 256) {
        int c = e / 112, w = e - c*112;
        T[c*113 + w] = xp[(size_t)c*12544 + w];
    }
    __syncthreads();
    if (tid < 224) {
        int w = tid >> 1, q = tid & 1;
        float s = 0.f, s2 = 0.f;
        for (int i = 0; i < 64; ++i) { float v = T[(q*64 + i)*113 + w]; s += v; s2 += v*v; }
        s  += __shfl_xor(s, 1, 64);
        s2 += __shfl_xor(s2, 1, 64);
        if (q == 0) {
            float m = s * 0.0078125f;
            float var = s2 * 0.0078125f - m*m;
            meanL[w] = m; rstdL[w] = rsqrtf(var + 1e-5f);
        }
    }
    __syncthreads();
    int hr = h + 109; if (hr >= 112) hr -= 112;
    int wh = hr / 7, nr = hr - wh*7;
    for (int e = tid; e < 14336; e += 256) {
        int w = e >> 7, c = e & 127;
        int wr = w + 109; if (wr >= 112) wr -= 112;
        int wwi = wr / 7, nc = wr - wwi*7;
        int win = b*256 + wh*16 + wwi;
        int n = nr*7 + nc;
        float v = (T[c*113 + w] - meanL[w]) * rstdL[w] * gL[c] + bL[c];
        xw[((size_t)win*64 + n)*128 + c] = (bf16)v;
    }
}

// ---------------- fused window attention v2 (unchanged from R3) ----------------
__global__ void __launch_bounds__(256, 4) k_attn(const bf16* __restrict__ xw,
                                              const bf16x8* __restrict__ wqkv,
                                              const float* __restrict__ qkv_b,
                                              const bf16x8* __restrict__ wproj,
                                              const float* __restrict__ proj_b,
                                              const float* __restrict__ bias49,
                                              bf16* __restrict__ x1p) {
    __shared__ char lds[49152];
    const int tid = threadIdx.x;
    const int l = tid & 63, wv = tid >> 6;
    const int win = blockIdx.x;
    const int lrow = l & 15, lk = l >> 4;
    char* X  = lds;
    char* VT = lds + wv*4096;
    char* Q  = lds + 16384 + wv*8192;
    char* Kt = Q + 4096;
    char* P  = Q;
    char* O  = lds + 16384;

    {
        const uint4* src = (const uint4*)(xw + (size_t)win*8192);
        for (int it = 0; it < 4; ++it) {
            int unit = it*256 + tid;
            int row = unit >> 4, s = unit & 15;
            *(uint4*)(X + swz256(row, s*16)) = src[unit];
        }
    }
    __syncthreads();

    {
        f32x4 qa[4][2], ka[4][2];
        float qb0 = qkv_b[      wv*32 + lrow], qb1 = qkv_b[      wv*32 + 16 + lrow];
        float kb0 = qkv_b[128 + wv*32 + lrow], kb1 = qkv_b[128 + wv*32 + 16 + lrow];
        for (int mf = 0; mf < 4; ++mf) for (int r = 0; r < 4; ++r) {
            qa[mf][0][r] = qb0; qa[mf][1][r] = qb1;
            ka[mf][0][r] = kb0; ka[mf][1][r] = kb1;
        }
        for (int kk = 0; kk < 4; ++kk) {
            bf16x8 a[4];
            for (int mf = 0; mf < 4; ++mf)
                a[mf] = *(const bf16x8*)(X + swz256(mf*16 + lrow, kk*64 + lk*16));
            for (int nf2 = 0; nf2 < 2; ++nf2) {
                bf16x8 bq = wqkv[(( (    wv*2 + nf2)*4 + kk)*64) + l];
                bf16x8 bk = wqkv[(( (8 + wv*2 + nf2)*4 + kk)*64) + l];
                for (int mf = 0; mf < 4; ++mf) {
                    qa[mf][nf2] = MFMA(a[mf], bq, qa[mf][nf2]);
                    ka[mf][nf2] = MFMA(a[mf], bk, ka[mf][nf2]);
                }
            }
        }
        const float scale = 0.17677669529663687f;
        for (int mf = 0; mf < 4; ++mf) for (int nf2 = 0; nf2 < 2; ++nf2)
            for (int r = 0; r < 4; ++r) {
                int row = mf*16 + lk*4 + r;
                int col = nf2*16 + lrow;
                *(bf16*)(Q  + swz64(row, col*2)) = (bf16)(qa[mf][nf2][r] * scale);
                *(bf16*)(Kt + swz64(row, col*2)) = (bf16)(ka[mf][nf2][r]);
            }
    }
    f32x4 va[4][2];
    {
        float vb0 = qkv_b[256 + wv*32 + lrow], vb1 = qkv_b[256 + wv*32 + 16 + lrow];
        for (int mf = 0; mf < 4; ++mf) for (int r = 0; r < 4; ++r) {
            va[mf][0][r] = vb0; va[mf][1][r] = vb1;
        }
        for (int kk = 0; kk < 4; ++kk) {
            bf16x8 a[4];
            for (int mf = 0; mf < 4; ++mf)
                a[mf] = *(const bf16x8*)(X + swz256(mf*16 + lrow, kk*64 + lk*16));
            for (int nf2 = 0; nf2 < 2; ++nf2) {
                bf16x8 bv = wqkv[(((16 + wv*2 + nf2)*4 + kk)*64) + l];
                for (int mf = 0; mf < 4; ++mf)
                    va[mf][nf2] = MFMA(a[mf], bv, va[mf][nf2]);
            }
        }
    }
    __syncthreads();
    for (int mf = 0; mf < 4; ++mf) for (int nf2 = 0; nf2 < 2; ++nf2)
        for (int r = 0; r < 4; ++r) {
            int row = mf*16 + lk*4 + r;
            int col = nf2*16 + lrow;
            *(bf16*)(VT + swz128(col, row*2)) = (bf16)(va[mf][nf2][r]);
        }

    f32x4 s[4][4];
    {
        const float* bh = bias49 + wv*2401;
        for (int mf = 0; mf < 4; ++mf) for (int nf = 0; nf < 4; ++nf)
            for (int r = 0; r < 4; ++r) {
                int row = mf*16 + lk*4 + r, col = nf*16 + lrow;
                float bv;
                if (col >= 49) bv = -1e30f;
                else if (row < 49) bv = bh[row*49 + col];
                else bv = 0.f;
                s[mf][nf][r] = bv;
            }
        bf16x8 aq[4], bk4[4];
        for (int mf = 0; mf < 4; ++mf) aq[mf]  = *(const bf16x8*)(Q  + swz64(mf*16 + lrow, lk*16));
        for (int nf = 0; nf < 4; ++nf) bk4[nf] = *(const bf16x8*)(Kt + swz64(nf*16 + lrow, lk*16));
        for (int mf = 0; mf < 4; ++mf) for (int nf = 0; nf < 4; ++nf)
            s[mf][nf] = MFMA(aq[mf], bk4[nf], s[mf][nf]);
    }
    for (int mf = 0; mf < 4; ++mf) for (int r = 0; r < 4; ++r) {
        float mx = -3e38f;
        for (int nf = 0; nf < 4; ++nf) mx = fmaxf(mx, s[mf][nf][r]);
        for (int d = 1; d < 16; d <<= 1) mx = fmaxf(mx, __shfl_xor(mx, d, 64));
        float sum = 0.f;
        for (int nf = 0; nf < 4; ++nf) { float p = __expf(s[mf][nf][r] - mx); s[mf][nf][r] = p; sum += p; }
        for (int d = 1; d < 16; d <<= 1) sum += __shfl_xor(sum, d, 64);
        float inv = 1.0f / sum;
        for (int nf = 0; nf < 4; ++nf) s[mf][nf][r] *= inv;
    }
    for (int mf = 0; mf < 4; ++mf) for (int nf = 0; nf < 4; ++nf)
        for (int r = 0; r < 4; ++r) {
            int row = mf*16 + lk*4 + r, col = nf*16 + lrow;
            *(bf16*)(P + swz128(row, col*2)) = (bf16)(s[mf][nf][r]);
        }

    f32x4 o[4][2];
    for (int mf = 0; mf < 4; ++mf) for (int nf = 0; nf < 2; ++nf)
        for (int r = 0; r < 4; ++r) o[mf][nf][r] = 0.f;
    for (int kf = 0; kf < 2; ++kf) {
        bf16x8 ap[4], bv2[2];
        for (int mf = 0; mf < 4; ++mf)
            ap[mf] = *(const bf16x8*)(P + swz128(mf*16 + lrow, kf*64 + lk*16));
        for (int nf = 0; nf < 2; ++nf)
            bv2[nf] = *(const bf16x8*)(VT + swz128(nf*16 + lrow, kf*64 + lk*16));
        for (int mf = 0; mf < 4; ++mf) for (int nf = 0; nf < 2; ++nf)
            o[mf][nf] = MFMA(ap[mf], bv2[nf], o[mf][nf]);
    }
    __syncthreads();
    for (int mf = 0; mf < 4; ++mf) for (int nf = 0; nf < 2; ++nf)
        for (int r = 0; r < 4; ++r) {
            int row = mf*16 + lk*4 + r, col = wv*32 + nf*16 + lrow;
            *(bf16*)(O + swz256(row, col*2)) = (bf16)(o[mf][nf][r]);
        }
    __syncthreads();

    f32x4 pr[4][2];
    {
        float pb0 = proj_b[wv*32 + lrow], pb1 = proj_b[wv*32 + 16 + lrow];
        for (int mf = 0; mf < 4; ++mf) for (int r = 0; r < 4; ++r) { pr[mf][0][r] = pb0; pr[mf][1][r] = pb1; }
    }
    for (int kk = 0; kk < 4; ++kk) {
        bf16x8 a[4];
        for (int mf = 0; mf < 4; ++mf)
            a[mf] = *(const bf16x8*)(O + swz256(mf*16 + lrow, kk*64 + lk*16));
        for (int nf = 0; nf < 2; ++nf) {
            bf16x8 bfr = wproj[(((wv*2 + nf)*4 + kk)*64) + l];
            for (int mf = 0; mf < 4; ++mf) pr[mf][nf] = MFMA(a[mf], bfr, pr[mf][nf]);
        }
    }
    {
        int b_ = win >> 8, wh = (win >> 4) & 15, ww = win & 15;
        for (int mf = 0; mf < 4; ++mf) for (int r = 0; r < 4; ++r) {
            int row = mf*16 + lk*4 + r;
            if (row < 49) {
                int nr = row / 7, nc = row - nr*7;
                int h = wh*7 + nr + 3; if (h >= 112) h -= 112;
                int w = ww*7 + nc + 3; if (w >= 112) w -= 112;
                size_t t = (size_t)b_*12544 + h*112 + w;
                for (int nf = 0; nf < 2; ++nf) {
                    int col = wv*32 + nf*16 + lrow;
                    x1p[t*128 + col] = (bf16)pr[mf][nf][r];
                }
            }
        }
    }
}

// ---------------- MLP v4: distributed phase-1, Xs-resident residual, zero epilogue re-reads ----------------
// one block per 64 tokens (1568 blocks), 4 waves; LDS 49408 B -> 3 blocks/CU
__global__ void __launch_bounds__(256, 4) k_mlp(const float* __restrict__ x,
                                             const bf16* __restrict__ x1p,
                                             const float* __restrict__ g2,
                                             const float* __restrict__ b2,
                                             const float* __restrict__ fc1_b,
                                             const float* __restrict__ fc2_b,
                                             const bf16x8* __restrict__ wfc1,
                                             const bf16x8* __restrict__ wfc2,
                                             float* __restrict__ out) {
    __shared__ char lds[49408];
    char* Xs = lds;                       // [64][128] bf16 swz256  (x1 = x + attn), lives whole kernel
    char* XN = lds + 16384;               // [64][128] bf16 swz256  (LN2 output)
    char* Hq = lds + 32768;               // [64][128] bf16 swz256  (hidden quarter)
    float* OT = (float*)(lds + 16384);    // [64][129] f32 overlay on XN+Hq (epilogue only)

    int tid = threadIdx.x;
    int l = tid & 63, wv = tid >> 6;
    int lrow = l & 15, lk = l >> 4;
    int blk = blockIdx.x;
    int b = blk / 196;
    int l0 = (blk - b*196) * 64;
    const float* xb = x + (size_t)b*128*12544 + l0;
    const bf16* xpb = x1p + ((size_t)b*12544 + l0)*128;

    // phase 1 (distributed: wave wv owns tokens wv*16+lrow; 4 lanes lk per token)
    {
        int t = wv*16 + lrow;
        float s = 0.f, s2 = 0.f;
        #pragma unroll
        for (int kk = 0; kk < 4; ++kk) {
            int c0 = kk*32 + lk*8;
            bf16x8 xpv = *(const bf16x8*)(xpb + t*128 + c0);
            bf16x8 v8;
            #pragma unroll
            for (int j = 0; j < 8; ++j) {
                float v = xb[(size_t)(c0+j)*12544 + t] + (float)xpv[j];
                s += v; s2 += v*v;
                v8[j] = (bf16)v;
            }
            *(bf16x8*)(Xs + swz256(t, kk*64 + lk*16)) = v8;
        }
        s  += __shfl_xor(s, 16, 64);  s  += __shfl_xor(s, 32, 64);
        s2 += __shfl_xor(s2, 16, 64); s2 += __shfl_xor(s2, 32, 64);
        float m = s * 0.0078125f;
        float var = s2 * 0.0078125f - m*m;
        float rs = rsqrtf(var + 1e-5f);
        #pragma unroll
        for (int kk = 0; kk < 4; ++kk) {
            int c0 = kk*32 + lk*8;
            bf16x8 v8 = *(const bf16x8*)(Xs + swz256(t, kk*64 + lk*16));
            float4 gv0 = *(const float4*)(g2 + c0), gv1 = *(const float4*)(g2 + c0 + 4);
            float4 bv0 = *(const float4*)(b2 + c0), bv1 = *(const float4*)(b2 + c0 + 4);
            float gg[8] = {gv0.x,gv0.y,gv0.z,gv0.w,gv1.x,gv1.y,gv1.z,gv1.w};
            float bb[8] = {bv0.x,bv0.y,bv0.z,bv0.w,bv1.x,bv1.y,bv1.z,bv1.w};
            #pragma unroll
            for (int j = 0; j < 8; ++j)
                v8[j] = (bf16)(((float)v8[j] - m) * rs * gg[j] + bb[j]);
            *(bf16x8*)(XN + swz256(t, kk*64 + lk*16)) = v8;
        }
    }
    __syncthreads();

    // FC1 -> GELU -> FC2 over 4 hidden quarters of 128
    f32x4 acc2[4][2];
    for (int mf = 0; mf < 4; ++mf) for (int nf = 0; nf < 2; ++nf) {
        float bv = fc2_b[wv*32 + nf*16 + lrow];
        for (int r = 0; r < 4; ++r) acc2[mf][nf][r] = bv;
    }
    for (int q = 0; q < 4; ++q) {
        f32x4 acc1[4][2];
        for (int mf = 0; mf < 4; ++mf) for (int nf = 0; nf < 2; ++nf) {
            float bv = fc1_b[q*128 + wv*32 + nf*16 + lrow];
            for (int r = 0; r < 4; ++r) acc1[mf][nf][r] = bv;
        }
        for (int kk = 0; kk < 4; ++kk) {
            bf16x8 a[4];
            for (int mf = 0; mf < 4; ++mf)
                a[mf] = *(const bf16x8*)(XN + swz256(mf*16 + lrow, kk*64 + lk*16));
            for (int nf = 0; nf < 2; ++nf) {
                int nfg = q*8 + wv*2 + nf;
                bf16x8 bw = wfc1[(nfg*4 + kk)*64 + l];
                for (int mf = 0; mf < 4; ++mf)
                    acc1[mf][nf] = MFMA(a[mf], bw, acc1[mf][nf]);
            }
        }
        if (q) __syncthreads();          // prior FC2 reads of Hq done
        for (int mf = 0; mf < 4; ++mf) for (int nf = 0; nf < 2; ++nf)
            for (int r = 0; r < 4; ++r) {
                int row = mf*16 + lk*4 + r, col = wv*32 + nf*16 + lrow;
                float v = acc1[mf][nf][r];
                float u = 0.7978845608f * (v + 0.044715f * v*v*v);
                float e2 = __expf(2.f * u);
                float th = 1.f - 2.f / (e2 + 1.f);
                v = 0.5f * v * (1.f + th);
                *(bf16*)(Hq + swz256(row, col*2)) = (bf16)v;
            }
        __syncthreads();
        for (int kk = 0; kk < 4; ++kk) {
            bf16x8 a[4];
            for (int mf = 0; mf < 4; ++mf)
                a[mf] = *(const bf16x8*)(Hq + swz256(mf*16 + lrow, kk*64 + lk*16));
            for (int nf = 0; nf < 2; ++nf) {
                bf16x8 bw = wfc2[(((wv*2 + nf)*16 + q*4 + kk)*64) + l];
                for (int mf = 0; mf < 4; ++mf)
                    acc2[mf][nf] = MFMA(a[mf], bw, acc2[mf][nf]);
            }
        }
    }
    __syncthreads();     // XN/Hq dead; OT overlays both

    // epilogue: out = acc2 + x1 (from Xs, no global re-reads); transpose via OT; float4 NCHW store
    for (int mf = 0; mf < 4; ++mf) for (int nf = 0; nf < 2; ++nf)
        for (int r = 0; r < 4; ++r) {
            int t = mf*16 + lk*4 + r, c = wv*32 + nf*16 + lrow;
            float v = acc2[mf][nf][r] + (float)*(const bf16*)(Xs + swz256(t, c*2));
            OT[t*129 + c] = v;
        }
    __syncthreads();
    for (int it = 0; it < 8; ++it) {
        int unit = it*256 + tid;
        int c = unit >> 4, i = unit & 15;
        float4 o;
        o.x = OT[(i*4+0)*129 + c];
        o.y = OT[(i*4+1)*129 + c];
        o.z = OT[(i*4+2)*129 + c];
        o.w = OT[(i*4+3)*129 + c];
        *(float4*)(out + (size_t)(b*128 + c)*12544 + l0 + i*4) = o;
    }
}

// ---------------- launch ----------------
extern "C" void kernel_launch(void* const* d_in, const int* in_sizes, int n_in,
                              void* d_out, int out_size, void* d_ws, size_t ws_size,
                              hipStream_t stream) {
    const float* x      = (const float*)d_in[0];
    const float* n1g    = (const float*)d_in[1];
    const float* n1b    = (const float*)d_in[2];
    const float* qkv_w  = (const float*)d_in[3];
    const float* qkv_b  = (const float*)d_in[4];
    const float* rtab   = (const float*)d_in[5];
    const int*   ridx   = (const int*)  d_in[6];
    const float* proj_w = (const float*)d_in[7];
    const float* proj_b = (const float*)d_in[8];
    const float* n2g    = (const float*)d_in[9];
    const float* n2b    = (const float*)d_in[10];
    const float* fc1_w  = (const float*)d_in[11];
    const float* fc1_b  = (const float*)d_in[12];
    const float* fc2_w  = (const float*)d_in[13];
    const float* fc2_b  = (const float*)d_in[14];
    float* out = (float*)d_out;
    char* ws = (char*)d_ws;

    bf16*  xw     = (bf16*)(ws);
    bf16*  x1p    = (bf16*)(ws + 33554432);
    bf16*  wqkv   = (bf16*)(ws + 59244544);
    bf16*  wproj  = (bf16*)(ws + 59342848);
    bf16*  wfc1   = (bf16*)(ws + 59375616);
    bf16*  wfc2   = (bf16*)(ws + 59506688);
    float* bias49 = (float*)(ws + 59637760);

    hipLaunchKernelGGL(k_pack, dim3(24), dim3(256), 0, stream, qkv_w,  wqkv,  128, 384);
    hipLaunchKernelGGL(k_pack, dim3(8),  dim3(256), 0, stream, proj_w, wproj, 128, 128);
    hipLaunchKernelGGL(k_pack, dim3(32), dim3(256), 0, stream, fc1_w,  wfc1,  128, 512);
    hipLaunchKernelGGL(k_pack, dim3(32), dim3(256), 0, stream, fc2_w,  wfc2,  512, 128);
    hipLaunchKernelGGL(k_bias, dim3(10), dim3(256), 0, stream, rtab, ridx, bias49);
    hipLaunchKernelGGL(k_zero, dim3(1920), dim3(256), 0, stream, (uint4*)xw);
    hipLaunchKernelGGL(k_ln1,  dim3(896),  dim3(256), 0, stream, x, n1g, n1b, xw);
    hipLaunchKernelGGL(k_attn, dim3(2048), dim3(256), 0, stream, xw, (const bf16x8*)wqkv,
                       qkv_b, (const bf16x8*)wproj, proj_b, bias49, x1p);
    hipLaunchKernelGGL(k_mlp,  dim3(1568), dim3(256), 0, stream, x, x1p, n2g, n2b,
                       fc1_b, fc2_b, (const bf16x8*)wfc1, (const bf16x8*)wfc2, out);
}